// Round 6
// baseline (1282.489 us; speedup 1.0000x reference)
//
#include <hip/hip_runtime.h>
#include <math.h>

#define NB 256      // events
#define NSV 64
#define NTRK 512
#define NPFC 512
#define KNN 8
#define HD 32

__device__ __forceinline__ float elu_f(float x) {
    return x > 0.f ? x : __expf(x) - 1.f;
}

// ---------------- encoder: out = elu(elu(x@W1+b1)@W2+b2) ----------------
template<int FIN>
__global__ __launch_bounds__(256) void encode_kernel(
    const float* __restrict__ x, const float* __restrict__ W1, const float* __restrict__ b1,
    const float* __restrict__ W2, const float* __restrict__ b2,
    float* __restrict__ out, int n_nodes)
{
    __shared__ float sW1[FIN * 32];
    __shared__ float sW2[32 * 32];
    __shared__ float sb1[32], sb2[32];
    __shared__ float sx[8][FIN];
    __shared__ float sh[8][32];
    int tid = threadIdx.x;
    for (int i = tid; i < FIN * 32; i += 256) sW1[i] = W1[i];
    for (int i = tid; i < 32 * 32; i += 256) sW2[i] = W2[i];
    if (tid < 32) { sb1[tid] = b1[tid]; sb2[tid] = b2[tid]; }
    int ln = tid >> 5, c = tid & 31;
    for (int it = 0; it < 4; it++) {
        int node0 = blockIdx.x * 32 + it * 8;
        __syncthreads();
        for (int i = tid; i < 8 * FIN; i += 256) {
            int nn = i / FIN, f = i - nn * FIN;
            int node = node0 + nn;
            sx[nn][f] = (node < n_nodes) ? x[(size_t)node * FIN + f] : 0.f;
        }
        __syncthreads();
        float h = sb1[c];
#pragma unroll
        for (int f = 0; f < FIN; f++) h = fmaf(sx[ln][f], sW1[f * 32 + c], h);
        h = elu_f(h);
        sh[ln][c] = h;
        __syncthreads();
        float o = sb2[c];
#pragma unroll
        for (int k = 0; k < 32; k++) o = fmaf(sh[ln][k], sW2[k * 32 + c], o);
        o = elu_f(o);
        int node = node0 + ln;
        if (node < n_nodes) out[(size_t)node * 32 + c] = o;
    }
}

// ---------------- weight prep: Wd = W[0:32]-W[32:64], W2h = W[32:64] ----------------
__global__ void prep_w_kernel(const float* __restrict__ W, const float* __restrict__ b,
                              float* __restrict__ wd, float* __restrict__ w2h,
                              float* __restrict__ bb)
{
    int i = threadIdx.x + blockIdx.x * blockDim.x;
    if (i < 1024) {
        float lo = W[i], hi = W[1024 + i];
        wd[i] = lo - hi;
        w2h[i] = hi;
    }
    if (i < 32) bb[i] = b[i];
}

// ---------------- kNN kernel: lanes = dst nodes, scalar src scan ----------
// One block = (event, half of dst): 4 waves x 64 lanes, one dst per lane.
// The src-row scan index is wave-uniform and src is const __restrict__ with
// no aliasing store in this kernel -> the compiler selects s_load; row data
// lives in SGPRs and feeds v_fma (1-SGPR-operand rule OK). This removes the
// round-5 bottleneck: 4096 broadcast ds_read_b128/wave on the LDS pipe
// (~164 us/CU). Norms go through a tiny 2KB LDS array (same fma chain as
// round 5 -> bit-identical kNN selection). Per-lane top-8 insertion kept.
template<int NS>
__global__ __launch_bounds__(256) void knn_kernel(
    const float* __restrict__ src, const float* __restrict__ dst,
    int* __restrict__ idx_out)
{
    __shared__ float s_nrm[NS];
    int b  = blockIdx.x >> 1;
    int hb = blockIdx.x & 1;
    int tid = threadIdx.x;
    int lane = tid & 63;
    int wave = tid >> 6;

    const float* srcb = src + (size_t)b * NS * 32;

    // norms: one row per thread, ascending-d fma chain (bit-exact vs r5)
    for (int s = tid; s < NS; s += 256) {
        const float4* r4 = (const float4*)(srcb + s * 32);
        float a = 0.f;
#pragma unroll
        for (int q = 0; q < 8; q++) {
            float4 v = r4[q];
            a = fmaf(v.x, v.x, a); a = fmaf(v.y, v.y, a);
            a = fmaf(v.z, v.z, a); a = fmaf(v.w, v.w, a);
        }
        s_nrm[s] = a;
    }
    __syncthreads();

    int t = hb * 256 + wave * 64 + lane;
    const float4* xi4 = (const float4*)(dst + ((size_t)b * 512 + t) * 32);
    float xd[32];
#pragma unroll
    for (int q = 0; q < 8; q++) {
        float4 v = xi4[q];
        xd[q*4+0] = v.x; xd[q*4+1] = v.y; xd[q*4+2] = v.z; xd[q*4+3] = v.w;
    }

    float val[KNN]; int idx[KNN];
#pragma unroll
    for (int k = 0; k < KNN; k++) { val[k] = 3.0e38f; idx[k] = 0; }

    const float4* sr4 = (const float4*)srcb;
    for (int s = 0; s < NS; s += 2) {
        float a0 = 0.f, a1 = 0.f, a2 = 0.f, a3 = 0.f;
        float b0 = 0.f, b1_ = 0.f, b2 = 0.f, b3 = 0.f;
#pragma unroll
        for (int q = 0; q < 8; q++) {
            float4 v = sr4[s * 8 + q];       // uniform addr -> s_load
            float4 w = sr4[s * 8 + 8 + q];   // uniform addr -> s_load
            a0 = fmaf(xd[q*4+0], v.x, a0); a1 = fmaf(xd[q*4+1], v.y, a1);
            a2 = fmaf(xd[q*4+2], v.z, a2); a3 = fmaf(xd[q*4+3], v.w, a3);
            b0 = fmaf(xd[q*4+0], w.x, b0); b1_ = fmaf(xd[q*4+1], w.y, b1_);
            b2 = fmaf(xd[q*4+2], w.z, b2); b3 = fmaf(xd[q*4+3], w.w, b3);
        }
        float dvA = s_nrm[s]     - 2.f * ((a0 + a1) + (a2 + a3));
        float dvB = s_nrm[s + 1] - 2.f * ((b0 + b1_) + (b2 + b3));
        if (dvA < val[KNN-1]) {
            bool c[KNN];
#pragma unroll
            for (int k = 0; k < KNN; k++) c[k] = dvA < val[k];
#pragma unroll
            for (int k = KNN-1; k >= 1; --k) {
                float tv = c[k-1] ? val[k-1] : dvA;
                int   ti = c[k-1] ? idx[k-1] : s;
                if (c[k]) { val[k] = tv; idx[k] = ti; }
            }
            if (c[0]) { val[0] = dvA; idx[0] = s; }
        }
        if (dvB < val[KNN-1]) {
            bool c[KNN];
#pragma unroll
            for (int k = 0; k < KNN; k++) c[k] = dvB < val[k];
#pragma unroll
            for (int k = KNN-1; k >= 1; --k) {
                float tv = c[k-1] ? val[k-1] : dvB;
                int   ti = c[k-1] ? idx[k-1] : (s + 1);
                if (c[k]) { val[k] = tv; idx[k] = ti; }
            }
            if (c[0]) { val[0] = dvB; idx[0] = s + 1; }
        }
    }

    int* op = idx_out + ((size_t)b * 512 + t) * 8;
#pragma unroll
    for (int k = 0; k < KNN; k++) op[k] = idx[k];
}

// ---------------- edge-MLP kernel: scalar gather + MLP + max-agg ----------
// Full wave per dst node (lane c = output column c, half-waves redundant).
// dst row, neighbor indices, and neighbor rows are all wave-uniform ->
// scalar loads; weights per-lane in VGPRs. No LDS at all. elu moved outside
// the max (elu monotone -> exact). Neighbors processed 2 at a time to bound
// SGPR pressure (~64 data SGPRs live).
template<int NS>
__global__ __launch_bounds__(256) void emlp_kernel(
    const float* __restrict__ src, const float* __restrict__ dst,
    const int* __restrict__ nbr,
    const float* __restrict__ Wd, const float* __restrict__ W2h,
    const float* __restrict__ bias, float* __restrict__ out)
{
    int b  = blockIdx.x >> 1;
    int hb = blockIdx.x & 1;
    int tid = threadIdx.x;
    int lane = tid & 63;
    int wave = tid >> 6;
    int c = lane & 31;

    float wdr[32], w2r[32];
#pragma unroll
    for (int d = 0; d < 32; d++) { wdr[d] = Wd[d * 32 + c]; w2r[d] = W2h[d * 32 + c]; }
    float bc = bias[c];
    const float* srcb = src + (size_t)b * NS * 32;

    for (int i = 0; i < 64; i++) {
        int t = hb * 256 + wave * 64 + i;
        const float* xr = dst + ((size_t)b * 512 + t) * 32;   // uniform -> s_load
        float base = bc;
#pragma unroll
        for (int d = 0; d < 32; d++) base = fmaf(xr[d], wdr[d], base);

        const int* ip = nbr + ((size_t)b * 512 + t) * 8;      // uniform -> s_load
        float mx = -3.0e38f;
#pragma unroll
        for (int k = 0; k < 8; k += 2) {
            int r0 = __builtin_amdgcn_readfirstlane(ip[k]);     // force SGPR
            int r1 = __builtin_amdgcn_readfirstlane(ip[k + 1]); // force SGPR
            const float* n0 = srcb + (size_t)r0 * 32;           // uniform -> s_load
            const float* n1 = srcb + (size_t)r1 * 32;
            float acc0 = base, acc1 = base;
#pragma unroll
            for (int d = 0; d < 32; d++) {
                acc0 = fmaf(n0[d], w2r[d], acc0);
                acc1 = fmaf(n1[d], w2r[d], acc1);
            }
            mx = fmaxf(mx, fmaxf(acc0, acc1));
        }
        float o = elu_f(mx);   // elu(max) == max(elu): elu monotone, exact
        if (lane < 32) out[((size_t)b * 512 + t) * 32 + c] = o;
    }
}

// ---------------- mean pool + out MLP + sigmoid + arange ----------------
__global__ __launch_bounds__(64) void final_kernel(
    const float* __restrict__ f3,
    const float* __restrict__ W1, const float* __restrict__ b1,
    const float* __restrict__ W2, const float* __restrict__ b2,
    float* __restrict__ outp)
{
    int b = blockIdx.x;
    int lane = threadIdx.x;
    int c = lane & 31, hh = lane >> 5;
    const float* base = f3 + (size_t)b * 512 * 32;
    float s = 0.f;
    for (int r = hh; r < 512; r += 2) s += base[r * 32 + c];
    s += __shfl_xor(s, 32);
    float pooled = s * (1.0f / 512.0f);
    __shared__ float sp[32];
    __shared__ float sh1[32];
    if (lane < 32) sp[c] = pooled;
    __syncthreads();
    if (lane < 32) {
        float h = b1[c];
#pragma unroll
        for (int d = 0; d < 32; d++) h = fmaf(sp[d], W1[d * 32 + c], h);
        sh1[c] = elu_f(h);
    }
    __syncthreads();
    if (lane == 0) {
        float o = b2[0];
#pragma unroll
        for (int d = 0; d < 32; d++) o = fmaf(sh1[d], W2[d], o);
        o = 1.f / (1.f + __expf(-o));
        outp[b] = o;                 // output 0: sigmoid [B,1]
        outp[NB + b] = (float)b;     // output 1: arange(B) read as float
    }
}

extern "C" void kernel_launch(void* const* d_in, const int* in_sizes, int n_in,
                              void* d_out, int out_size, void* d_ws, size_t ws_size,
                              hipStream_t stream) {
    const float* x_sv  = (const float*)d_in[0];
    const float* x_trk = (const float*)d_in[1];
    const float* x_pfc = (const float*)d_in[2];
    const float* sv_W1  = (const float*)d_in[6];
    const float* sv_b1  = (const float*)d_in[7];
    const float* sv_W2  = (const float*)d_in[8];
    const float* sv_b2  = (const float*)d_in[9];
    const float* trk_W1 = (const float*)d_in[10];
    const float* trk_b1 = (const float*)d_in[11];
    const float* trk_W2 = (const float*)d_in[12];
    const float* trk_b2 = (const float*)d_in[13];
    const float* pfc_W1 = (const float*)d_in[14];
    const float* pfc_b1 = (const float*)d_in[15];
    const float* pfc_W2 = (const float*)d_in[16];
    const float* pfc_b2 = (const float*)d_in[17];
    const float* conv_W = (const float*)d_in[18];
    const float* conv_b = (const float*)d_in[19];
    const float* out_W1 = (const float*)d_in[20];
    const float* out_b1 = (const float*)d_in[21];
    const float* out_W2 = (const float*)d_in[22];
    const float* out_b2 = (const float*)d_in[23];

    float* ws = (float*)d_ws;
    const size_t SV_E  = (size_t)NB * NSV * HD;
    const size_t TRK_E = (size_t)NB * NTRK * HD;
    float* sv_enc  = ws;
    float* trk_enc = sv_enc + SV_E;
    float* pfc_enc = trk_enc + TRK_E;
    float* f1      = pfc_enc + TRK_E;
    float* f2      = f1 + TRK_E;
    float* wd      = f2 + TRK_E;
    float* w2h     = wd + 1024;
    float* bb      = w2h + 1024;
    int*   knn_idx = (int*)(bb + 64);          // [B,512,8] = 1M ints
    float* f3      = trk_enc;  // trk_enc dead after conv2 -> reuse

    prep_w_kernel<<<1, 1024, 0, stream>>>(conv_W, conv_b, wd, w2h, bb);

    encode_kernel<14><<<(NB * NSV) / 32, 256, 0, stream>>>(x_sv, sv_W1, sv_b1, sv_W2, sv_b2, sv_enc, NB * NSV);
    encode_kernel<30><<<(NB * NTRK) / 32, 256, 0, stream>>>(x_trk, trk_W1, trk_b1, trk_W2, trk_b2, trk_enc, NB * NTRK);
    encode_kernel<10><<<(NB * NPFC) / 32, 256, 0, stream>>>(x_pfc, pfc_W1, pfc_b1, pfc_W2, pfc_b2, pfc_enc, NB * NPFC);

    // conv1: sv -> trk
    knn_kernel<64>  <<<NB * 2, 256, 0, stream>>>(sv_enc, trk_enc, knn_idx);
    emlp_kernel<64> <<<NB * 2, 256, 0, stream>>>(sv_enc, trk_enc, knn_idx, wd, w2h, bb, f1);
    // conv2: pfc -> trk
    knn_kernel<512> <<<NB * 2, 256, 0, stream>>>(pfc_enc, trk_enc, knn_idx);
    emlp_kernel<512><<<NB * 2, 256, 0, stream>>>(pfc_enc, trk_enc, knn_idx, wd, w2h, bb, f2);
    // conv3: f1 -> f2
    knn_kernel<512> <<<NB * 2, 256, 0, stream>>>(f1, f2, knn_idx);
    emlp_kernel<512><<<NB * 2, 256, 0, stream>>>(f1, f2, knn_idx, wd, w2h, bb, f3);

    final_kernel<<<NB, 64, 0, stream>>>(f3, out_W1, out_b1, out_W2, out_b2, (float*)d_out);
}

// Round 7
// 828.460 us; speedup vs baseline: 1.5480x; 1.5480x over previous
//
#include <hip/hip_runtime.h>
#include <math.h>

#define NB 256      // events
#define NSV 64
#define NTRK 512
#define NPFC 512
#define KNN 8
#define HD 32

__device__ __forceinline__ float elu_f(float x) {
    return x > 0.f ? x : __expf(x) - 1.f;
}

// ---------------- encoder: out = elu(elu(x@W1+b1)@W2+b2) ----------------
template<int FIN>
__global__ __launch_bounds__(256) void encode_kernel(
    const float* __restrict__ x, const float* __restrict__ W1, const float* __restrict__ b1,
    const float* __restrict__ W2, const float* __restrict__ b2,
    float* __restrict__ out, int n_nodes)
{
    __shared__ float sW1[FIN * 32];
    __shared__ float sW2[32 * 32];
    __shared__ float sb1[32], sb2[32];
    __shared__ float sx[8][FIN];
    __shared__ float sh[8][32];
    int tid = threadIdx.x;
    for (int i = tid; i < FIN * 32; i += 256) sW1[i] = W1[i];
    for (int i = tid; i < 32 * 32; i += 256) sW2[i] = W2[i];
    if (tid < 32) { sb1[tid] = b1[tid]; sb2[tid] = b2[tid]; }
    int ln = tid >> 5, c = tid & 31;
    for (int it = 0; it < 4; it++) {
        int node0 = blockIdx.x * 32 + it * 8;
        __syncthreads();
        for (int i = tid; i < 8 * FIN; i += 256) {
            int nn = i / FIN, f = i - nn * FIN;
            int node = node0 + nn;
            sx[nn][f] = (node < n_nodes) ? x[(size_t)node * FIN + f] : 0.f;
        }
        __syncthreads();
        float h = sb1[c];
#pragma unroll
        for (int f = 0; f < FIN; f++) h = fmaf(sx[ln][f], sW1[f * 32 + c], h);
        h = elu_f(h);
        sh[ln][c] = h;
        __syncthreads();
        float o = sb2[c];
#pragma unroll
        for (int k = 0; k < 32; k++) o = fmaf(sh[ln][k], sW2[k * 32 + c], o);
        o = elu_f(o);
        int node = node0 + ln;
        if (node < n_nodes) out[(size_t)node * 32 + c] = o;
    }
}

// ---------------- weight prep: Wd = W[0:32]-W[32:64], W2h = W[32:64] ----------------
__global__ void prep_w_kernel(const float* __restrict__ W, const float* __restrict__ b,
                              float* __restrict__ wd, float* __restrict__ w2h,
                              float* __restrict__ bb)
{
    int i = threadIdx.x + blockIdx.x * blockDim.x;
    if (i < 1024) {
        float lo = W[i], hi = W[1024 + i];
        wd[i] = lo - hi;
        w2h[i] = hi;
    }
    if (i < 32) bb[i] = b[i];
}

// ---------------- kNN kernel: per-lane dst, 2 dst/lane, LDS broadcast ------
// One block = one EVENT (512 dst): 4 waves x 64 lanes x 2 dst. Each broadcast
// src quad feeds 8 FMAs (2 dst x 4 elems) -> half the LDS instructions per
// dst vs round 5 (its bottleneck). Distance fma chains identical to rounds
// 4-6 -> bit-identical selection. Live regs ~110 (xd 64 + 8 acc + 32 sel)
// -> fits the 128-VGPR budget, no spill.
template<int NS>
__global__ __launch_bounds__(256) void knn_kernel(
    const float* __restrict__ src, const float* __restrict__ dst,
    int* __restrict__ idx_out)
{
    __shared__ float4 s_src[NS * 8];
    __shared__ float  s_nrm[NS];
    int b = blockIdx.x;
    int tid = threadIdx.x;
    int lane = tid & 63;
    int wave = tid >> 6;

    const float4* src4 = (const float4*)(src + (size_t)b * NS * 32);
    for (int i = tid; i < NS * 8; i += 256) s_src[i] = src4[i];
    __syncthreads();
    for (int s = tid; s < NS; s += 256) {
        float a = 0.f;
#pragma unroll
        for (int q = 0; q < 8; q++) {
            float4 v = s_src[s * 8 + q];
            a = fmaf(v.x, v.x, a); a = fmaf(v.y, v.y, a);
            a = fmaf(v.z, v.z, a); a = fmaf(v.w, v.w, a);
        }
        s_nrm[s] = a;
    }
    __syncthreads();

    int t0 = wave * 64 + lane;      // dst 0..255
    int t1 = t0 + 256;              // dst 256..511
    const float4* xi0 = (const float4*)(dst + ((size_t)b * 512 + t0) * 32);
    const float4* xi1 = (const float4*)(dst + ((size_t)b * 512 + t1) * 32);
    float xd0[32], xd1[32];
#pragma unroll
    for (int q = 0; q < 8; q++) {
        float4 v = xi0[q];
        xd0[q*4+0] = v.x; xd0[q*4+1] = v.y; xd0[q*4+2] = v.z; xd0[q*4+3] = v.w;
        float4 w = xi1[q];
        xd1[q*4+0] = w.x; xd1[q*4+1] = w.y; xd1[q*4+2] = w.z; xd1[q*4+3] = w.w;
    }

    float val0[KNN], val1[KNN]; int idx0[KNN], idx1[KNN];
#pragma unroll
    for (int k = 0; k < KNN; k++) {
        val0[k] = 3.0e38f; idx0[k] = 0;
        val1[k] = 3.0e38f; idx1[k] = 0;
    }

    for (int s = 0; s < NS; s++) {
        float a0 = 0.f, a1 = 0.f, a2 = 0.f, a3 = 0.f;   // dst0
        float c0 = 0.f, c1 = 0.f, c2 = 0.f, c3 = 0.f;   // dst1
#pragma unroll
        for (int q = 0; q < 8; q++) {
            float4 v = s_src[s * 8 + q];                 // broadcast read
            a0 = fmaf(xd0[q*4+0], v.x, a0); a1 = fmaf(xd0[q*4+1], v.y, a1);
            a2 = fmaf(xd0[q*4+2], v.z, a2); a3 = fmaf(xd0[q*4+3], v.w, a3);
            c0 = fmaf(xd1[q*4+0], v.x, c0); c1 = fmaf(xd1[q*4+1], v.y, c1);
            c2 = fmaf(xd1[q*4+2], v.z, c2); c3 = fmaf(xd1[q*4+3], v.w, c3);
        }
        float nrm = s_nrm[s];
        float dv0 = nrm - 2.f * ((a0 + a1) + (a2 + a3));
        float dv1 = nrm - 2.f * ((c0 + c1) + (c2 + c3));
        if (dv0 < val0[KNN-1]) {
            bool c[KNN];
#pragma unroll
            for (int k = 0; k < KNN; k++) c[k] = dv0 < val0[k];
#pragma unroll
            for (int k = KNN-1; k >= 1; --k) {
                float tv = c[k-1] ? val0[k-1] : dv0;
                int   ti = c[k-1] ? idx0[k-1] : s;
                if (c[k]) { val0[k] = tv; idx0[k] = ti; }
            }
            if (c[0]) { val0[0] = dv0; idx0[0] = s; }
        }
        if (dv1 < val1[KNN-1]) {
            bool c[KNN];
#pragma unroll
            for (int k = 0; k < KNN; k++) c[k] = dv1 < val1[k];
#pragma unroll
            for (int k = KNN-1; k >= 1; --k) {
                float tv = c[k-1] ? val1[k-1] : dv1;
                int   ti = c[k-1] ? idx1[k-1] : s;
                if (c[k]) { val1[k] = tv; idx1[k] = ti; }
            }
            if (c[0]) { val1[0] = dv1; idx1[0] = s; }
        }
    }

    int* o0 = idx_out + ((size_t)b * 512 + t0) * 8;
    int* o1 = idx_out + ((size_t)b * 512 + t1) * 8;
#pragma unroll
    for (int k = 0; k < KNN; k++) { o0[k] = idx0[k]; o1[k] = idx1[k]; }
}

// ---------------- Y & Base precompute ------------------------------------
// Edge MLP is LINEAR in x_j: m[k][c] = Base[t][c] + Y[sel_k][c] with
// Y = src @ W2h (no bias), Base = dst @ Wd + b. This kernel computes both:
// blocks [0, nblocksY) do Y rows, the rest do Base rows. 64 rows/block.
__global__ __launch_bounds__(256) void yb_kernel(
    const float* __restrict__ srcY, const float* __restrict__ w2h,
    const float* __restrict__ dstB, const float* __restrict__ wd,
    const float* __restrict__ bb,
    float* __restrict__ Y, float* __restrict__ Bse, int nblocksY)
{
    __shared__ float sW[1024];
    __shared__ float sb[32];
    __shared__ float sx[8][32];
    int tid = threadIdx.x;
    bool isY = (int)blockIdx.x < nblocksY;
    const float* W = isY ? w2h : wd;
    const float* X = isY ? srcY : dstB;
    float* O = isY ? Y : Bse;
    int rb = (isY ? blockIdx.x : blockIdx.x - nblocksY) * 64;

    for (int i = tid; i < 1024; i += 256) sW[i] = W[i];
    if (tid < 32) sb[tid] = isY ? 0.f : bb[tid];
    int ln = tid >> 5, c = tid & 31;
    for (int p = 0; p < 8; p++) {
        __syncthreads();
        int row = rb + p * 8 + ln;
        sx[tid >> 5][tid & 31] = X[(size_t)(rb + p * 8 + (tid >> 5)) * 32 + (tid & 31)];
        __syncthreads();
        float acc = sb[c];
#pragma unroll
        for (int d = 0; d < 32; d++) acc = fmaf(sx[ln][d], sW[d * 32 + c], acc);
        O[(size_t)row * 32 + c] = acc;
    }
}

// ---------------- gather + max + elu -------------------------------------
// One thread per dst node. Gathers its 8 neighbors' Y rows (per-lane
// dwordx4 vector loads, L2-resident: Y is 64KB/event), running max, adds
// Base, elu. out[t][c] = elu(Base[t][c] + max_k Y[sel_k][c])  (elu monotone
// + Base constant over k -> exactly max_k elu(Base + Y_k)).
__global__ __launch_bounds__(256) void gather_kernel(
    const float* __restrict__ Y, const float* __restrict__ Bse,
    const int* __restrict__ nbr, float* __restrict__ out, int NSs)
{
    int t = blockIdx.x * 256 + threadIdx.x;     // 0 .. NB*512-1
    int e = t >> 9;
    const float4* Yb = (const float4*)(Y + (size_t)e * NSs * 32);
    const int4* ip = (const int4*)(nbr + (size_t)t * 8);
    int4 i0 = ip[0], i1 = ip[1];
    int rows[8] = { i0.x, i0.y, i0.z, i0.w, i1.x, i1.y, i1.z, i1.w };

    float4 m[8];
    {
        const float4* r = Yb + (size_t)rows[0] * 8;
#pragma unroll
        for (int q = 0; q < 8; q++) m[q] = r[q];
    }
#pragma unroll
    for (int k = 1; k < 8; k++) {
        const float4* r = Yb + (size_t)rows[k] * 8;
#pragma unroll
        for (int q = 0; q < 8; q++) {
            float4 v = r[q];
            m[q].x = fmaxf(m[q].x, v.x); m[q].y = fmaxf(m[q].y, v.y);
            m[q].z = fmaxf(m[q].z, v.z); m[q].w = fmaxf(m[q].w, v.w);
        }
    }
    const float4* bp = (const float4*)(Bse + (size_t)t * 32);
    float4* op = (float4*)(out + (size_t)t * 32);
#pragma unroll
    for (int q = 0; q < 8; q++) {
        float4 bv = bp[q];
        float4 o;
        o.x = elu_f(bv.x + m[q].x); o.y = elu_f(bv.y + m[q].y);
        o.z = elu_f(bv.z + m[q].z); o.w = elu_f(bv.w + m[q].w);
        op[q] = o;
    }
}

// ---------------- mean pool + out MLP + sigmoid + arange ----------------
__global__ __launch_bounds__(64) void final_kernel(
    const float* __restrict__ f3,
    const float* __restrict__ W1, const float* __restrict__ b1,
    const float* __restrict__ W2, const float* __restrict__ b2,
    float* __restrict__ outp)
{
    int b = blockIdx.x;
    int lane = threadIdx.x;
    int c = lane & 31, hh = lane >> 5;
    const float* base = f3 + (size_t)b * 512 * 32;
    float s = 0.f;
    for (int r = hh; r < 512; r += 2) s += base[r * 32 + c];
    s += __shfl_xor(s, 32);
    float pooled = s * (1.0f / 512.0f);
    __shared__ float sp[32];
    __shared__ float sh1[32];
    if (lane < 32) sp[c] = pooled;
    __syncthreads();
    if (lane < 32) {
        float h = b1[c];
#pragma unroll
        for (int d = 0; d < 32; d++) h = fmaf(sp[d], W1[d * 32 + c], h);
        sh1[c] = elu_f(h);
    }
    __syncthreads();
    if (lane == 0) {
        float o = b2[0];
#pragma unroll
        for (int d = 0; d < 32; d++) o = fmaf(sh1[d], W2[d], o);
        o = 1.f / (1.f + __expf(-o));
        outp[b] = o;                 // output 0: sigmoid [B,1]
        outp[NB + b] = (float)b;     // output 1: arange(B) read as float
    }
}

extern "C" void kernel_launch(void* const* d_in, const int* in_sizes, int n_in,
                              void* d_out, int out_size, void* d_ws, size_t ws_size,
                              hipStream_t stream) {
    const float* x_sv  = (const float*)d_in[0];
    const float* x_trk = (const float*)d_in[1];
    const float* x_pfc = (const float*)d_in[2];
    const float* sv_W1  = (const float*)d_in[6];
    const float* sv_b1  = (const float*)d_in[7];
    const float* sv_W2  = (const float*)d_in[8];
    const float* sv_b2  = (const float*)d_in[9];
    const float* trk_W1 = (const float*)d_in[10];
    const float* trk_b1 = (const float*)d_in[11];
    const float* trk_W2 = (const float*)d_in[12];
    const float* trk_b2 = (const float*)d_in[13];
    const float* pfc_W1 = (const float*)d_in[14];
    const float* pfc_b1 = (const float*)d_in[15];
    const float* pfc_W2 = (const float*)d_in[16];
    const float* pfc_b2 = (const float*)d_in[17];
    const float* conv_W = (const float*)d_in[18];
    const float* conv_b = (const float*)d_in[19];
    const float* out_W1 = (const float*)d_in[20];
    const float* out_b1 = (const float*)d_in[21];
    const float* out_W2 = (const float*)d_in[22];
    const float* out_b2 = (const float*)d_in[23];

    float* ws = (float*)d_ws;
    const size_t SV_E  = (size_t)NB * NSV * HD;    //  524288
    const size_t TRK_E = (size_t)NB * NTRK * HD;   // 4194304
    float* sv_enc  = ws;
    float* trk_enc = sv_enc + SV_E;
    float* pfc_enc = trk_enc + TRK_E;
    float* f1      = pfc_enc + TRK_E;
    float* f2      = f1 + TRK_E;
    float* wd      = f2 + TRK_E;
    float* w2h     = wd + 1024;
    float* bb      = w2h + 1024;
    int*   knn_idx = (int*)(bb + 64);              // NB*512*8 ints
    float* Ybuf    = (float*)(knn_idx) + (size_t)NB * 512 * 8;
    float* Bse     = Ybuf + TRK_E;
    float* f3      = trk_enc;  // trk_enc dead after conv2's yb -> reuse

    prep_w_kernel<<<1, 1024, 0, stream>>>(conv_W, conv_b, wd, w2h, bb);

    encode_kernel<14><<<(NB * NSV) / 32, 256, 0, stream>>>(x_sv, sv_W1, sv_b1, sv_W2, sv_b2, sv_enc, NB * NSV);
    encode_kernel<30><<<(NB * NTRK) / 32, 256, 0, stream>>>(x_trk, trk_W1, trk_b1, trk_W2, trk_b2, trk_enc, NB * NTRK);
    encode_kernel<10><<<(NB * NPFC) / 32, 256, 0, stream>>>(x_pfc, pfc_W1, pfc_b1, pfc_W2, pfc_b2, pfc_enc, NB * NPFC);

    const int nbY_sv  = (NB * NSV) / 64;    //  256
    const int nbY_big = (NB * NTRK) / 64;   // 2048
    const int nbB     = (NB * 512) / 64;    // 2048
    const int gblocks = (NB * 512) / 256;   //  512

    // conv1: sv -> trk
    knn_kernel<64><<<NB, 256, 0, stream>>>(sv_enc, trk_enc, knn_idx);
    yb_kernel<<<nbY_sv + nbB, 256, 0, stream>>>(sv_enc, w2h, trk_enc, wd, bb, Ybuf, Bse, nbY_sv);
    gather_kernel<<<gblocks, 256, 0, stream>>>(Ybuf, Bse, knn_idx, f1, NSV);
    // conv2: pfc -> trk
    knn_kernel<512><<<NB, 256, 0, stream>>>(pfc_enc, trk_enc, knn_idx);
    yb_kernel<<<nbY_big + nbB, 256, 0, stream>>>(pfc_enc, w2h, trk_enc, wd, bb, Ybuf, Bse, nbY_big);
    gather_kernel<<<gblocks, 256, 0, stream>>>(Ybuf, Bse, knn_idx, f2, NPFC);
    // conv3: f1 -> f2
    knn_kernel<512><<<NB, 256, 0, stream>>>(f1, f2, knn_idx);
    yb_kernel<<<nbY_big + nbB, 256, 0, stream>>>(f1, w2h, f2, wd, bb, Ybuf, Bse, nbY_big);
    gather_kernel<<<gblocks, 256, 0, stream>>>(Ybuf, Bse, knn_idx, f3, NTRK);

    final_kernel<<<NB, 64, 0, stream>>>(f3, out_W1, out_b1, out_W2, out_b2, (float*)d_out);
}

// Round 8
// 705.479 us; speedup vs baseline: 1.8179x; 1.1743x over previous
//
#include <hip/hip_runtime.h>
#include <math.h>

#define NB 256      // events
#define NSV 64
#define NTRK 512
#define NPFC 512
#define KNN 8
#define HD 32

__device__ __forceinline__ float elu_f(float x) {
    return x > 0.f ? x : __expf(x) - 1.f;
}

// ---------------- encoder: out = elu(elu(x@W1+b1)@W2+b2) ----------------
template<int FIN>
__global__ __launch_bounds__(256) void encode_kernel(
    const float* __restrict__ x, const float* __restrict__ W1, const float* __restrict__ b1,
    const float* __restrict__ W2, const float* __restrict__ b2,
    float* __restrict__ out, int n_nodes)
{
    __shared__ float sW1[FIN * 32];
    __shared__ float sW2[32 * 32];
    __shared__ float sb1[32], sb2[32];
    __shared__ float sx[8][FIN];
    __shared__ float sh[8][32];
    int tid = threadIdx.x;
    for (int i = tid; i < FIN * 32; i += 256) sW1[i] = W1[i];
    for (int i = tid; i < 32 * 32; i += 256) sW2[i] = W2[i];
    if (tid < 32) { sb1[tid] = b1[tid]; sb2[tid] = b2[tid]; }
    int ln = tid >> 5, c = tid & 31;
    for (int it = 0; it < 4; it++) {
        int node0 = blockIdx.x * 32 + it * 8;
        __syncthreads();
        for (int i = tid; i < 8 * FIN; i += 256) {
            int nn = i / FIN, f = i - nn * FIN;
            int node = node0 + nn;
            sx[nn][f] = (node < n_nodes) ? x[(size_t)node * FIN + f] : 0.f;
        }
        __syncthreads();
        float h = sb1[c];
#pragma unroll
        for (int f = 0; f < FIN; f++) h = fmaf(sx[ln][f], sW1[f * 32 + c], h);
        h = elu_f(h);
        sh[ln][c] = h;
        __syncthreads();
        float o = sb2[c];
#pragma unroll
        for (int k = 0; k < 32; k++) o = fmaf(sh[ln][k], sW2[k * 32 + c], o);
        o = elu_f(o);
        int node = node0 + ln;
        if (node < n_nodes) out[(size_t)node * 32 + c] = o;
    }
}

// ---------------- weight prep ----------------
__global__ void prep_w_kernel(const float* __restrict__ W, const float* __restrict__ b,
                              float* __restrict__ wd, float* __restrict__ w2h,
                              float* __restrict__ bb)
{
    int i = threadIdx.x + blockIdx.x * blockDim.x;
    if (i < 1024) {
        float lo = W[i], hi = W[1024 + i];
        wd[i] = lo - hi;
        w2h[i] = hi;
    }
    if (i < 32) bb[i] = b[i];
}

// ---------------- small kNN (NS=64): one block per event (round-7 form) ---
__global__ __launch_bounds__(256) void knn_small_kernel(
    const float* __restrict__ src, const float* __restrict__ dst,
    int* __restrict__ idx_out)
{
    constexpr int NS = 64;
    __shared__ float4 s_src[NS * 8];
    __shared__ float  s_nrm[NS];
    int b = blockIdx.x;
    int tid = threadIdx.x;
    int lane = tid & 63;
    int wave = tid >> 6;

    const float4* src4 = (const float4*)(src + (size_t)b * NS * 32);
    for (int i = tid; i < NS * 8; i += 256) s_src[i] = src4[i];
    __syncthreads();
    for (int s = tid; s < NS; s += 256) {
        float a = 0.f;
#pragma unroll
        for (int q = 0; q < 8; q++) {
            float4 v = s_src[s * 8 + q];
            a = fmaf(v.x, v.x, a); a = fmaf(v.y, v.y, a);
            a = fmaf(v.z, v.z, a); a = fmaf(v.w, v.w, a);
        }
        s_nrm[s] = a;
    }
    __syncthreads();

    int t0 = wave * 64 + lane;
    int t1 = t0 + 256;
    const float4* xi0 = (const float4*)(dst + ((size_t)b * 512 + t0) * 32);
    const float4* xi1 = (const float4*)(dst + ((size_t)b * 512 + t1) * 32);
    float xd0[32], xd1[32];
#pragma unroll
    for (int q = 0; q < 8; q++) {
        float4 v = xi0[q];
        xd0[q*4+0] = v.x; xd0[q*4+1] = v.y; xd0[q*4+2] = v.z; xd0[q*4+3] = v.w;
        float4 w = xi1[q];
        xd1[q*4+0] = w.x; xd1[q*4+1] = w.y; xd1[q*4+2] = w.z; xd1[q*4+3] = w.w;
    }

    float val0[KNN], val1[KNN]; int idx0[KNN], idx1[KNN];
#pragma unroll
    for (int k = 0; k < KNN; k++) {
        val0[k] = 3.0e38f; idx0[k] = 0;
        val1[k] = 3.0e38f; idx1[k] = 0;
    }

    for (int s = 0; s < NS; s++) {
        float a0 = 0.f, a1 = 0.f, a2 = 0.f, a3 = 0.f;
        float c0 = 0.f, c1 = 0.f, c2 = 0.f, c3 = 0.f;
#pragma unroll
        for (int q = 0; q < 8; q++) {
            float4 v = s_src[s * 8 + q];
            a0 = fmaf(xd0[q*4+0], v.x, a0); a1 = fmaf(xd0[q*4+1], v.y, a1);
            a2 = fmaf(xd0[q*4+2], v.z, a2); a3 = fmaf(xd0[q*4+3], v.w, a3);
            c0 = fmaf(xd1[q*4+0], v.x, c0); c1 = fmaf(xd1[q*4+1], v.y, c1);
            c2 = fmaf(xd1[q*4+2], v.z, c2); c3 = fmaf(xd1[q*4+3], v.w, c3);
        }
        float nrm = s_nrm[s];
        float dv0 = nrm - 2.f * ((a0 + a1) + (a2 + a3));
        float dv1 = nrm - 2.f * ((c0 + c1) + (c2 + c3));
        if (dv0 < val0[KNN-1]) {
            bool c[KNN];
#pragma unroll
            for (int k = 0; k < KNN; k++) c[k] = dv0 < val0[k];
#pragma unroll
            for (int k = KNN-1; k >= 1; --k) {
                float tv = c[k-1] ? val0[k-1] : dv0;
                int   ti = c[k-1] ? idx0[k-1] : s;
                if (c[k]) { val0[k] = tv; idx0[k] = ti; }
            }
            if (c[0]) { val0[0] = dv0; idx0[0] = s; }
        }
        if (dv1 < val1[KNN-1]) {
            bool c[KNN];
#pragma unroll
            for (int k = 0; k < KNN; k++) c[k] = dv1 < val1[k];
#pragma unroll
            for (int k = KNN-1; k >= 1; --k) {
                float tv = c[k-1] ? val1[k-1] : dv1;
                int   ti = c[k-1] ? idx1[k-1] : s;
                if (c[k]) { val1[k] = tv; idx1[k] = ti; }
            }
            if (c[0]) { val1[0] = dv1; idx1[0] = s; }
        }
    }

    int* o0 = idx_out + ((size_t)b * 512 + t0) * 8;
    int* o1 = idx_out + ((size_t)b * 512 + t1) * 8;
#pragma unroll
    for (int k = 0; k < KNN; k++) { o0[k] = idx0[k]; o1[k] = idx1[k]; }
}

// ---------------- split kNN (NS=512): src rows split in halves ------------
// grid = NB*2: block (b, half) scans rows [half*256, half*256+256) for ALL
// 512 dst of event b (dpl=2). LDS 33KB -> 2 blocks/CU -> 8 waves/CU (the
// round-7 version had 4 waves/CU and stalled on unhidden LDS latency).
// Emits per-dst partial sorted top-8: val fp32 + global row idx u16. The
// final merge lives in gather_kernel (strict <, half0 first == single
// ascending scan semantics; distances bit-identical per-row chains).
__global__ __launch_bounds__(256) void knn_split_kernel(
    const float* __restrict__ src, const float* __restrict__ dst,
    float* __restrict__ pval, unsigned int* __restrict__ pidx)
{
    constexpr int HR = 256;
    __shared__ float4 s_src[HR * 8];
    __shared__ float  s_nrm[HR];
    int b    = blockIdx.x >> 1;
    int half = blockIdx.x & 1;
    int tid = threadIdx.x;
    int lane = tid & 63;
    int wave = tid >> 6;

    const float4* src4 = (const float4*)(src + ((size_t)b * 512 + half * HR) * 32);
    for (int i = tid; i < HR * 8; i += 256) s_src[i] = src4[i];
    __syncthreads();
    for (int s = tid; s < HR; s += 256) {
        float a = 0.f;
#pragma unroll
        for (int q = 0; q < 8; q++) {
            float4 v = s_src[s * 8 + q];
            a = fmaf(v.x, v.x, a); a = fmaf(v.y, v.y, a);
            a = fmaf(v.z, v.z, a); a = fmaf(v.w, v.w, a);
        }
        s_nrm[s] = a;
    }
    __syncthreads();

    int t0 = wave * 64 + lane;
    int t1 = t0 + 256;
    const float4* xi0 = (const float4*)(dst + ((size_t)b * 512 + t0) * 32);
    const float4* xi1 = (const float4*)(dst + ((size_t)b * 512 + t1) * 32);
    float xd0[32], xd1[32];
#pragma unroll
    for (int q = 0; q < 8; q++) {
        float4 v = xi0[q];
        xd0[q*4+0] = v.x; xd0[q*4+1] = v.y; xd0[q*4+2] = v.z; xd0[q*4+3] = v.w;
        float4 w = xi1[q];
        xd1[q*4+0] = w.x; xd1[q*4+1] = w.y; xd1[q*4+2] = w.z; xd1[q*4+3] = w.w;
    }

    float val0[KNN], val1[KNN]; int idx0[KNN], idx1[KNN];
#pragma unroll
    for (int k = 0; k < KNN; k++) {
        val0[k] = 3.0e38f; idx0[k] = 0;
        val1[k] = 3.0e38f; idx1[k] = 0;
    }

    for (int s = 0; s < HR; s++) {
        float a0 = 0.f, a1 = 0.f, a2 = 0.f, a3 = 0.f;
        float c0 = 0.f, c1 = 0.f, c2 = 0.f, c3 = 0.f;
#pragma unroll
        for (int q = 0; q < 8; q++) {
            float4 v = s_src[s * 8 + q];
            a0 = fmaf(xd0[q*4+0], v.x, a0); a1 = fmaf(xd0[q*4+1], v.y, a1);
            a2 = fmaf(xd0[q*4+2], v.z, a2); a3 = fmaf(xd0[q*4+3], v.w, a3);
            c0 = fmaf(xd1[q*4+0], v.x, c0); c1 = fmaf(xd1[q*4+1], v.y, c1);
            c2 = fmaf(xd1[q*4+2], v.z, c2); c3 = fmaf(xd1[q*4+3], v.w, c3);
        }
        float nrm = s_nrm[s];
        float dv0 = nrm - 2.f * ((a0 + a1) + (a2 + a3));
        float dv1 = nrm - 2.f * ((c0 + c1) + (c2 + c3));
        if (dv0 < val0[KNN-1]) {
            bool c[KNN];
#pragma unroll
            for (int k = 0; k < KNN; k++) c[k] = dv0 < val0[k];
#pragma unroll
            for (int k = KNN-1; k >= 1; --k) {
                float tv = c[k-1] ? val0[k-1] : dv0;
                int   ti = c[k-1] ? idx0[k-1] : s;
                if (c[k]) { val0[k] = tv; idx0[k] = ti; }
            }
            if (c[0]) { val0[0] = dv0; idx0[0] = s; }
        }
        if (dv1 < val1[KNN-1]) {
            bool c[KNN];
#pragma unroll
            for (int k = 0; k < KNN; k++) c[k] = dv1 < val1[k];
#pragma unroll
            for (int k = KNN-1; k >= 1; --k) {
                float tv = c[k-1] ? val1[k-1] : dv1;
                int   ti = c[k-1] ? idx1[k-1] : s;
                if (c[k]) { val1[k] = tv; idx1[k] = ti; }
            }
            if (c[0]) { val1[0] = dv1; idx1[0] = s; }
        }
    }

    int base = half * HR;
    // pval layout: [t][half][8] floats; pidx: [t][half][8] u16 packed 2/word
    {
        float* pv = pval + ((size_t)b * 512 + t0) * 16 + half * 8;
        unsigned int* pi = pidx + (((size_t)b * 512 + t0) * 16 + half * 8) / 2;
#pragma unroll
        for (int k = 0; k < KNN; k++) pv[k] = val0[k];
#pragma unroll
        for (int k = 0; k < 4; k++)
            pi[k] = (unsigned)(idx0[2*k] + base) | ((unsigned)(idx0[2*k+1] + base) << 16);
    }
    {
        float* pv = pval + ((size_t)b * 512 + t1) * 16 + half * 8;
        unsigned int* pi = pidx + (((size_t)b * 512 + t1) * 16 + half * 8) / 2;
#pragma unroll
        for (int k = 0; k < KNN; k++) pv[k] = val1[k];
#pragma unroll
        for (int k = 0; k < 4; k++)
            pi[k] = (unsigned)(idx1[2*k] + base) | ((unsigned)(idx1[2*k+1] + base) << 16);
    }
}

// ---------------- Y & Base precompute ------------------------------------
// Y = src @ W2h (no bias) -> Ybuf; Base = dst @ Wd + b -> written IN-PLACE
// into the conv's output buffer f (gather later does f = elu(f + max Y)).
__global__ __launch_bounds__(256) void yb_kernel(
    const float* __restrict__ srcY, const float* __restrict__ w2h,
    const float* __restrict__ dstB, const float* __restrict__ wd,
    const float* __restrict__ bb,
    float* __restrict__ Y, float* __restrict__ fout, int nblocksY)
{
    __shared__ float sW[1024];
    __shared__ float sb[32];
    __shared__ float sx[8][32];
    int tid = threadIdx.x;
    bool isY = (int)blockIdx.x < nblocksY;
    const float* W = isY ? w2h : wd;
    const float* X = isY ? srcY : dstB;
    float* O = isY ? Y : fout;
    int rb = (isY ? blockIdx.x : blockIdx.x - nblocksY) * 64;

    for (int i = tid; i < 1024; i += 256) sW[i] = W[i];
    if (tid < 32) sb[tid] = isY ? 0.f : bb[tid];
    int ln = tid >> 5, c = tid & 31;
    for (int p = 0; p < 8; p++) {
        __syncthreads();
        int row = rb + p * 8 + ln;
        sx[tid >> 5][tid & 31] = X[(size_t)(rb + p * 8 + (tid >> 5)) * 32 + (tid & 31)];
        __syncthreads();
        float acc = sb[c];
#pragma unroll
        for (int d = 0; d < 32; d++) acc = fmaf(sx[ln][d], sW[d * 32 + c], acc);
        O[(size_t)row * 32 + c] = acc;
    }
}

// ---------------- gather (+ optional merge) + max + elu -------------------
// One thread per dst node, in-place on f: f[t] = elu(f[t] + max_k Y[row_k]).
// MERGE=true: rows come from merging the two partial sorted lists (strict <,
// half0-first == exact single-scan tie semantics). MERGE=false: rows from
// the int32 nbr list (conv1).
template<bool MERGE>
__global__ __launch_bounds__(256) void gather_kernel(
    const float* __restrict__ Y,
    const int* __restrict__ nbr,
    const float* __restrict__ pval, const unsigned int* __restrict__ pidx,
    float* __restrict__ f, int NSs)
{
    int t = blockIdx.x * 256 + threadIdx.x;
    int e = t >> 9;
    int rows[8];
    if (MERGE) {
        const float4* pv = (const float4*)(pval + (size_t)t * 16);
        float4 v0 = pv[0], v1 = pv[1], v2 = pv[2], v3 = pv[3];
        const uint4* pi = (const uint4*)(pidx + (size_t)t * 8);
        uint4 u0 = pi[0], u1 = pi[1];
        float val[8] = { v0.x, v0.y, v0.z, v0.w, v1.x, v1.y, v1.z, v1.w };
        int   idx[8] = { (int)(u0.x & 0xffff), (int)(u0.x >> 16),
                         (int)(u0.y & 0xffff), (int)(u0.y >> 16),
                         (int)(u0.z & 0xffff), (int)(u0.z >> 16),
                         (int)(u0.w & 0xffff), (int)(u0.w >> 16) };
        float cva[8] = { v2.x, v2.y, v2.z, v2.w, v3.x, v3.y, v3.z, v3.w };
        int   cia[8] = { (int)(u1.x & 0xffff), (int)(u1.x >> 16),
                         (int)(u1.y & 0xffff), (int)(u1.y >> 16),
                         (int)(u1.z & 0xffff), (int)(u1.z >> 16),
                         (int)(u1.w & 0xffff), (int)(u1.w >> 16) };
#pragma unroll
        for (int j = 0; j < 8; j++) {
            float cv = cva[j]; int ci = cia[j];
            if (cv < val[7]) {
                bool c[8];
#pragma unroll
                for (int k = 0; k < 8; k++) c[k] = cv < val[k];
#pragma unroll
                for (int k = 7; k >= 1; --k) {
                    float tv = c[k-1] ? val[k-1] : cv;
                    int   ti = c[k-1] ? idx[k-1] : ci;
                    if (c[k]) { val[k] = tv; idx[k] = ti; }
                }
                if (c[0]) { val[0] = cv; idx[0] = ci; }
            }
        }
#pragma unroll
        for (int k = 0; k < 8; k++) rows[k] = idx[k];
    } else {
        const int4* ip = (const int4*)(nbr + (size_t)t * 8);
        int4 i0 = ip[0], i1 = ip[1];
        rows[0] = i0.x; rows[1] = i0.y; rows[2] = i0.z; rows[3] = i0.w;
        rows[4] = i1.x; rows[5] = i1.y; rows[6] = i1.z; rows[7] = i1.w;
    }

    const float4* Yb = (const float4*)(Y + (size_t)e * NSs * 32);
    float4 m[8];
    {
        const float4* r = Yb + (size_t)rows[0] * 8;
#pragma unroll
        for (int q = 0; q < 8; q++) m[q] = r[q];
    }
#pragma unroll
    for (int k = 1; k < 8; k++) {
        const float4* r = Yb + (size_t)rows[k] * 8;
#pragma unroll
        for (int q = 0; q < 8; q++) {
            float4 v = r[q];
            m[q].x = fmaxf(m[q].x, v.x); m[q].y = fmaxf(m[q].y, v.y);
            m[q].z = fmaxf(m[q].z, v.z); m[q].w = fmaxf(m[q].w, v.w);
        }
    }
    float4* op = (float4*)(f + (size_t)t * 32);
#pragma unroll
    for (int q = 0; q < 8; q++) {
        float4 bv = op[q];
        float4 o;
        o.x = elu_f(bv.x + m[q].x); o.y = elu_f(bv.y + m[q].y);
        o.z = elu_f(bv.z + m[q].z); o.w = elu_f(bv.w + m[q].w);
        op[q] = o;
    }
}

// ---------------- mean pool + out MLP + sigmoid + arange ----------------
__global__ __launch_bounds__(64) void final_kernel(
    const float* __restrict__ f3,
    const float* __restrict__ W1, const float* __restrict__ b1,
    const float* __restrict__ W2, const float* __restrict__ b2,
    float* __restrict__ outp)
{
    int b = blockIdx.x;
    int lane = threadIdx.x;
    int c = lane & 31, hh = lane >> 5;
    const float* base = f3 + (size_t)b * 512 * 32;
    float s = 0.f;
    for (int r = hh; r < 512; r += 2) s += base[r * 32 + c];
    s += __shfl_xor(s, 32);
    float pooled = s * (1.0f / 512.0f);
    __shared__ float sp[32];
    __shared__ float sh1[32];
    if (lane < 32) sp[c] = pooled;
    __syncthreads();
    if (lane < 32) {
        float h = b1[c];
#pragma unroll
        for (int d = 0; d < 32; d++) h = fmaf(sp[d], W1[d * 32 + c], h);
        sh1[c] = elu_f(h);
    }
    __syncthreads();
    if (lane == 0) {
        float o = b2[0];
#pragma unroll
        for (int d = 0; d < 32; d++) o = fmaf(sh1[d], W2[d], o);
        o = 1.f / (1.f + __expf(-o));
        outp[b] = o;
        outp[NB + b] = (float)b;
    }
}

extern "C" void kernel_launch(void* const* d_in, const int* in_sizes, int n_in,
                              void* d_out, int out_size, void* d_ws, size_t ws_size,
                              hipStream_t stream) {
    const float* x_sv  = (const float*)d_in[0];
    const float* x_trk = (const float*)d_in[1];
    const float* x_pfc = (const float*)d_in[2];
    const float* sv_W1  = (const float*)d_in[6];
    const float* sv_b1  = (const float*)d_in[7];
    const float* sv_W2  = (const float*)d_in[8];
    const float* sv_b2  = (const float*)d_in[9];
    const float* trk_W1 = (const float*)d_in[10];
    const float* trk_b1 = (const float*)d_in[11];
    const float* trk_W2 = (const float*)d_in[12];
    const float* trk_b2 = (const float*)d_in[13];
    const float* pfc_W1 = (const float*)d_in[14];
    const float* pfc_b1 = (const float*)d_in[15];
    const float* pfc_W2 = (const float*)d_in[16];
    const float* pfc_b2 = (const float*)d_in[17];
    const float* conv_W = (const float*)d_in[18];
    const float* conv_b = (const float*)d_in[19];
    const float* out_W1 = (const float*)d_in[20];
    const float* out_b1 = (const float*)d_in[21];
    const float* out_W2 = (const float*)d_in[22];
    const float* out_b2 = (const float*)d_in[23];

    float* ws = (float*)d_ws;
    const size_t SV_E  = (size_t)NB * NSV * HD;    //  524288
    const size_t TRK_E = (size_t)NB * NTRK * HD;   // 4194304
    float* sv_enc  = ws;
    float* trk_enc = sv_enc + SV_E;
    float* pfc_enc = trk_enc + TRK_E;
    float* f1      = pfc_enc + TRK_E;
    float* f2      = f1 + TRK_E;
    float* wd      = f2 + TRK_E;
    float* w2h     = wd + 1024;
    float* bb      = w2h + 1024;
    // idx region: conv1 int32 knn_idx (NB*512*8 ints) == conv2/3 u16 pidx
    // (NB*512*16 u16) — identical 4.19MB footprint, disjoint lifetimes.
    int*   knn_idx = (int*)(bb + 64);
    unsigned int* pidx = (unsigned int*)knn_idx;
    float* pval    = (float*)(knn_idx + (size_t)NB * 512 * 8);  // 8.4MB
    float* Ybuf    = pval + (size_t)NB * 512 * 16;
    float* f3      = trk_enc;  // trk_enc dead after conv2 -> reuse

    prep_w_kernel<<<1, 1024, 0, stream>>>(conv_W, conv_b, wd, w2h, bb);

    encode_kernel<14><<<(NB * NSV) / 32, 256, 0, stream>>>(x_sv, sv_W1, sv_b1, sv_W2, sv_b2, sv_enc, NB * NSV);
    encode_kernel<30><<<(NB * NTRK) / 32, 256, 0, stream>>>(x_trk, trk_W1, trk_b1, trk_W2, trk_b2, trk_enc, NB * NTRK);
    encode_kernel<10><<<(NB * NPFC) / 32, 256, 0, stream>>>(x_pfc, pfc_W1, pfc_b1, pfc_W2, pfc_b2, pfc_enc, NB * NPFC);

    const int nbY_sv  = (NB * NSV) / 64;    //  256
    const int nbY_big = (NB * NTRK) / 64;   // 2048
    const int nbB     = (NB * 512) / 64;    // 2048
    const int gblocks = (NB * 512) / 256;   //  512

    // conv1: sv -> trk
    knn_small_kernel<<<NB, 256, 0, stream>>>(sv_enc, trk_enc, knn_idx);
    yb_kernel<<<nbY_sv + nbB, 256, 0, stream>>>(sv_enc, w2h, trk_enc, wd, bb, Ybuf, f1, nbY_sv);
    gather_kernel<false><<<gblocks, 256, 0, stream>>>(Ybuf, knn_idx, nullptr, nullptr, f1, NSV);
    // conv2: pfc -> trk
    knn_split_kernel<<<NB * 2, 256, 0, stream>>>(pfc_enc, trk_enc, pval, pidx);
    yb_kernel<<<nbY_big + nbB, 256, 0, stream>>>(pfc_enc, w2h, trk_enc, wd, bb, Ybuf, f2, nbY_big);
    gather_kernel<true><<<gblocks, 256, 0, stream>>>(Ybuf, nullptr, pval, pidx, f2, NPFC);
    // conv3: f1 -> f2
    knn_split_kernel<<<NB * 2, 256, 0, stream>>>(f1, f2, pval, pidx);
    yb_kernel<<<nbY_big + nbB, 256, 0, stream>>>(f1, w2h, f2, wd, bb, Ybuf, f3, nbY_big);
    gather_kernel<true><<<gblocks, 256, 0, stream>>>(Ybuf, nullptr, pval, pidx, f3, NTRK);

    final_kernel<<<NB, 64, 0, stream>>>(f3, out_W1, out_b1, out_W2, out_b2, (float*)d_out);
}